// Round 4
// baseline (44.463 us; speedup 1.0000x reference)
//
#include <hip/hip_runtime.h>
#include <hip/hip_bf16.h>
#include <cstddef>

#define D_IN 512
#define BLOCK 256
#define RPB 32     // rows per block (4 waves x 8 rows)

// ---------------------------------------------------------------------------
// Gate helpers (used only in the pre-kernel). Template params keep state[]
// indices compile-time. Wire q (PennyLane: wire 0 most significant) = bit 3-q.
// ---------------------------------------------------------------------------
template<int BIT>
__device__ __forceinline__ void applyG(float* sr, float* si,
    float u00r, float u00i, float u01r, float u01i,
    float u10r, float u10i, float u11r, float u11i)
{
#pragma unroll
    for (int m = 0; m < 8; ++m) {
        const int lo = m & (BIT - 1);
        const int i0 = ((m ^ lo) << 1) | lo;
        const int i1 = i0 | BIT;
        float a0r = sr[i0], a0i = si[i0];
        float a1r = sr[i1], a1i = si[i1];
        float n0r = u00r * a0r - u00i * a0i + u01r * a1r - u01i * a1i;
        float n0i = u00r * a0i + u00i * a0r + u01r * a1i + u01i * a1r;
        float n1r = u10r * a0r - u10i * a0i + u11r * a1r - u11i * a1i;
        float n1i = u10r * a0i + u10i * a0r + u11r * a1i + u11i * a1r;
        sr[i0] = n0r; si[i0] = n0i;
        sr[i1] = n1r; si[i1] = n1i;
    }
}

template<int CB, int TB>
__device__ __forceinline__ void applyCNOT(float* sr, float* si)
{
    constexpr int FREE = 15 & ~CB & ~TB;
    constexpr int LO = FREE & (-FREE);
    constexpr int HI = FREE ^ LO;
#pragma unroll
    for (int m = 0; m < 4; ++m) {
        const int idx = CB | ((m & 1) ? LO : 0) | ((m & 2) ? HI : 0);
        const int j = idx | TB;
        float tr = sr[idx]; sr[idx] = sr[j]; sr[j] = tr;
        float ti = si[idx]; si[idx] = si[j]; si[j] = ti;
    }
}

// ---------------------------------------------------------------------------
// Pre-kernel: build M (16x16 real symmetric, batch-invariant) such that
// out(row) = r^T M r, where r[idx] = prod_q (bit_q(idx) ? sin(a_q/2)
// : cos(a_q/2)). Derivation: embedded state amp = (-i)^pop(idx) * r[idx];
// final = U*amp = V*r with V[:,j] = (-i)^pop(j) U[:,j] (U = fixed entangler);
// out = sum_k w_k |final_k|^2 = r^T [sum_k w_k (VR_k VR_k^T + VI_k VI_k^T)] r,
// w_k = 1 - popcount(k)/2.
// Thread j (j<16) builds U's column j by applying the gate sequence to e_j.
// ---------------------------------------------------------------------------
__global__ void qhead_pre(const float* __restrict__ w, float* __restrict__ M)
{
    __shared__ float VR[16][16], VI[16][16];
    const int j = threadIdx.x;

    // Rot matrices rm[g][8]: [u00r,u00i,u01r,u01i,u10r,u10i,u11r,u11i]
    float rm[8][8];
#pragma unroll
    for (int g = 0; g < 8; ++g) {
        float phi = w[g * 3 + 0];
        float th  = w[g * 3 + 1];
        float om  = w[g * 3 + 2];
        float sn, cs;  sincosf(th * 0.5f, &sn, &cs);
        float sa, ca;  sincosf((phi + om) * 0.5f, &sa, &ca);
        float sd, cd;  sincosf((phi - om) * 0.5f, &sd, &cd);
        rm[g][0] =  cs * ca;  rm[g][1] = -cs * sa;
        rm[g][2] = -sn * cd;  rm[g][3] = -sn * sd;
        rm[g][4] =  sn * cd;  rm[g][5] = -sn * sd;
        rm[g][6] =  cs * ca;  rm[g][7] =  cs * sa;
    }

    if (j < 16) {
        float sr[16], si[16];
#pragma unroll
        for (int i = 0; i < 16; ++i) { sr[i] = 0.f; si[i] = 0.f; }
        sr[j] = 1.f;   // basis state e_j

#define ROTG(l, q)                                                          \
    applyG<(1 << (3 - (q)))>(sr, si,                                        \
        rm[(l) * 4 + (q)][0], rm[(l) * 4 + (q)][1], rm[(l) * 4 + (q)][2],   \
        rm[(l) * 4 + (q)][3], rm[(l) * 4 + (q)][4], rm[(l) * 4 + (q)][5],   \
        rm[(l) * 4 + (q)][6], rm[(l) * 4 + (q)][7]);

        // Layer 0: Rot each wire, CNOT ring range 1
        ROTG(0, 0); ROTG(0, 1); ROTG(0, 2); ROTG(0, 3);
        applyCNOT<8, 4>(sr, si);
        applyCNOT<4, 2>(sr, si);
        applyCNOT<2, 1>(sr, si);
        applyCNOT<1, 8>(sr, si);
        // Layer 1: Rot each wire, CNOT ring range 2
        ROTG(1, 0); ROTG(1, 1); ROTG(1, 2); ROTG(1, 3);
        applyCNOT<8, 2>(sr, si);
        applyCNOT<4, 1>(sr, si);
        applyCNOT<2, 8>(sr, si);
        applyCNOT<1, 4>(sr, si);
#undef ROTG

        // V[:,j] = (-i)^pop(j) * U[:,j]
        const int pm = __popc(j) & 3;
#pragma unroll
        for (int k = 0; k < 16; ++k) {
            float re = sr[k], im = si[k], vr, vi;
            if      (pm == 0) { vr =  re; vi =  im; }
            else if (pm == 1) { vr =  im; vi = -re; }
            else if (pm == 2) { vr = -re; vi = -im; }
            else              { vr = -im; vi =  re; }
            VR[k][j] = vr;  VI[k][j] = vi;
        }
    }
    __syncthreads();
    if (j < 16) {
#pragma unroll
        for (int b = 0; b < 16; ++b) {
            float acc = 0.f;
#pragma unroll
            for (int k = 0; k < 16; ++k) {
                float wk = 1.0f - 0.5f * (float)__popc(k);
                acc += wk * (VR[k][j] * VR[k][b] + VI[k][j] * VI[k][b]);
            }
            M[j * 16 + b] = acc;
        }
    }
}

// ---------------------------------------------------------------------------
// Main fused kernel. Block = 256 thr / 4 waves / 32 rows.
// GEMM phase: wave handles 8 rows in 4 passes of 2; lane sub (=lane&31) owns
// k-chunk sub (coalesced 512B segments per row), weights in registers,
// 2-deep software pipeline on the x loads. Partial dots -> LDS (no shuffles).
// Reduce phase: 128 threads tree-sum the 32 partials per (row,j), bias+tanh.
// Sim phase: 32 threads compute r (8 sincos-derived products) and r^T M r.
// ---------------------------------------------------------------------------
__global__ __launch_bounds__(BLOCK) void qhead_main(
    const float* __restrict__ x,
    const float* __restrict__ fc_w,
    const float* __restrict__ fc_b,
    const float* __restrict__ Mg,
    float* __restrict__ out, int B)
{
    __shared__ float part[RPB][4][36];   // [row][j][sub], pad 36 keeps 16B align
    __shared__ float ang[RPB][4];
    __shared__ float Mlds[256];

    const int t    = threadIdx.x;
    Mlds[t] = Mg[t];

    const int lane = t & 63;
    const int wv   = t >> 6;
    const int sub  = lane & 31;
    const int half = lane >> 5;
    const int row0 = blockIdx.x * RPB + wv * 8;   // wave's first global row

    // weights: 16 float4 regs per lane (row j, chunk it*32+sub)
    const float4* w4 = (const float4*)fc_w;
    float4 wreg[4][4];
#pragma unroll
    for (int jj = 0; jj < 4; ++jj)
#pragma unroll
        for (int it = 0; it < 4; ++it)
            wreg[jj][it] = w4[jj * 128 + it * 32 + sub];

    // clamped global rows for the 4 passes (straight-line, no branches)
    int rp0 = row0 + 0 + half; if (rp0 >= B) rp0 = B - 1;
    int rp1 = row0 + 2 + half; if (rp1 >= B) rp1 = B - 1;
    int rp2 = row0 + 4 + half; if (rp2 >= B) rp2 = B - 1;
    int rp3 = row0 + 6 + half; if (rp3 >= B) rp3 = B - 1;
    const float4* x4 = (const float4*)x;

#define LOADX(dst, r)                                                       \
    {                                                                       \
        const float4* xr = x4 + (size_t)(r) * 128 + sub;                    \
        dst[0] = xr[0]; dst[1] = xr[32]; dst[2] = xr[64]; dst[3] = xr[96];  \
    }
#define PASS(p, xv)                                                         \
    {                                                                       \
        float s0 = 0.f, s1 = 0.f, s2 = 0.f, s3 = 0.f;                       \
        _Pragma("unroll")                                                   \
        for (int it = 0; it < 4; ++it) {                                    \
            float4 v = xv[it];                                              \
            s0 += v.x * wreg[0][it].x + v.y * wreg[0][it].y                 \
                + v.z * wreg[0][it].z + v.w * wreg[0][it].w;                \
            s1 += v.x * wreg[1][it].x + v.y * wreg[1][it].y                 \
                + v.z * wreg[1][it].z + v.w * wreg[1][it].w;                \
            s2 += v.x * wreg[2][it].x + v.y * wreg[2][it].y                 \
                + v.z * wreg[2][it].z + v.w * wreg[2][it].w;                \
            s3 += v.x * wreg[3][it].x + v.y * wreg[3][it].y                 \
                + v.z * wreg[3][it].z + v.w * wreg[3][it].w;                \
        }                                                                   \
        const int lr = wv * 8 + (p) * 2 + half;                             \
        part[lr][0][sub] = s0;  part[lr][1][sub] = s1;                      \
        part[lr][2][sub] = s2;  part[lr][3][sub] = s3;                      \
    }

    float4 xvA[4], xvB[4];
    LOADX(xvA, rp0);
    LOADX(xvB, rp1);
    PASS(0, xvA);
    LOADX(xvA, rp2);
    PASS(1, xvB);
    LOADX(xvB, rp3);
    PASS(2, xvA);
    PASS(3, xvB);
#undef LOADX
#undef PASS

    __syncthreads();

    // ---- reduce: thread t<128 handles (row = t>>2, j = t&3) ----
    if (t < 128) {
        const int row = t >> 2, jj = t & 3;
        const float4* pv = (const float4*)&part[row][jj][0];
        float4 a = pv[0];
#pragma unroll
        for (int u = 1; u < 8; ++u) {
            float4 b = pv[u];
            a.x += b.x; a.y += b.y; a.z += b.z; a.w += b.w;
        }
        float s = (a.x + a.y) + (a.z + a.w);
        ang[row][jj] = tanhf(s + fc_b[jj]);
    }
    __syncthreads();

    // ---- sim: thread t<32 finishes its row via r^T M r ----
    if (t < 32) {
        const int grow = blockIdx.x * RPB + t;
        float c[4], s[4];
#pragma unroll
        for (int q = 0; q < 4; ++q)
            sincosf(ang[t][q] * 0.5f, &s[q], &c[q]);

        // r[idx]: bit3=wire0 .. bit0=wire3
        float rA[4] = { c[0]*c[1], c[0]*s[1], s[0]*c[1], s[0]*s[1] };
        float rB[4] = { c[2]*c[3], c[2]*s[3], s[2]*c[3], s[2]*s[3] };
        float r[16];
#pragma unroll
        for (int u = 0; u < 4; ++u)
#pragma unroll
            for (int v = 0; v < 4; ++v)
                r[u * 4 + v] = rA[u] * rB[v];

        const float4* M4 = (const float4*)Mlds;
        float res = 0.f;
#pragma unroll
        for (int a = 0; a < 16; ++a) {
            float ta = 0.f;
#pragma unroll
            for (int bq = 0; bq < 4; ++bq) {
                float4 m = M4[a * 4 + bq];
                ta += m.x * r[bq * 4 + 0] + m.y * r[bq * 4 + 1]
                    + m.z * r[bq * 4 + 2] + m.w * r[bq * 4 + 3];
            }
            res += ta * r[a];
        }
        if (grow < B) out[grow] = res;
    }
}

extern "C" void kernel_launch(void* const* d_in, const int* in_sizes, int n_in,
                              void* d_out, int out_size, void* d_ws, size_t ws_size,
                              hipStream_t stream)
{
    const float* x    = (const float*)d_in[0];
    const float* fc_w = (const float*)d_in[1];
    const float* fc_b = (const float*)d_in[2];
    const float* w    = (const float*)d_in[3];
    float* out = (float*)d_out;
    float* M   = (float*)d_ws;           // 256 floats

    const int B = in_sizes[0] / D_IN;

    qhead_pre<<<1, 64, 0, stream>>>(w, M);
    qhead_main<<<(B + RPB - 1) / RPB, BLOCK, 0, stream>>>(
        x, fc_w, fc_b, M, out, B);
}